// Round 3
// baseline (169.714 us; speedup 1.0000x reference)
//
#include <hip/hip_runtime.h>
#include <math.h>

typedef _Float16 h2_t __attribute__((ext_vector_type(2)));
typedef _Float16 h4_t __attribute__((ext_vector_type(4)));
typedef _Float16 h8_t __attribute__((ext_vector_type(8)));
typedef float    f2_t __attribute__((ext_vector_type(2)));

#define NP 32
#define KC 31
#define HH 512
#define WW 512
#define BB 4
#define CC 3

#define TXO 64        // 64-wide tile, 512-thread block
#define TYO 32
#define NT 512        // threads per block
#define TROWS 62      // 32 outputs + 15 + 15 halo
#define TWORDS 48     // f16 tile row stride in h2 words (96 halves)
#define TILEW (TROWS * TWORDS)   // 2976 h2 words per channel tile
#define WSTR 36       // weight table plane stride in h2 words
#define FSTR 96       // f32 staging buffer row stride in floats
#define FROWS 64      // padded to 64 rows so FROWS*FSTR = 6144 = 12*NT exactly
#define FBUFW (FROWS * FSTR)

// HARD CONSTRAINTS (measured): grid z = BB; >128 VGPRs unobtainable; insert-
// style unpack; fdot2 == pk_fma rate -> inner dy-loop is FINAL.
// R1/R2 POST-MORTEM: ANY register state live across the dy-loop spills
// (R2: WRITE_SIZE 12->52MB, kernel scratch-bound). THIS ROUND: zero-register
// pipelining via global_load_lds -> f32 LDS staging buffer (fire-and-forget,
// vmcnt-tracked, no VGPRs). Channel c+1 streams into fbuf DURING channel c's
// compute; a ~1us LDS->LDS convert pass (identical RNE f16 rounding + identical
// OOB zero-masking) produces the f16 tile after the post-compute barrier.
// gll global addresses are CLAMPED in-range (no per-lane predicate exists);
// garbage halo values are masked to 0 at convert time, matching R0 exactly.

__device__ __forceinline__ double plane_of(int i) {
    const double stepd = 50.0 / 31.0;
    return (i < 31) ? (double)i * stepd : 50.0;
}

// Stage one channel: 12 global_load_lds_dword per thread, zero registers live.
// LDS dest = fbuf + f with f = tid + i*NT: per wave this is uniform base +
// lane*4B, the required linear pattern. Global addr clamped into the image.
__device__ __forceinline__ void issue_stage(const float* __restrict__ src,
                                            float* fbuf, int tid,
                                            int tiley, int tilex) {
    #pragma unroll
    for (int i = 0; i < 12; ++i) {
        const int f = tid + i * NT;          // 0..6143, exact (12*512 = FBUFW)
        const int r = f / FSTR;              // 0..63
        const int w = f - r * FSTR;          // 0..95
        int gy = tiley - 15 + r;  gy = min(max(gy, 0), HH - 1);
        int gx = tilex - 15 + w;  gx = min(max(gx, 0), WW - 1);
        const float* gp = src + gy * WW + gx;
        __builtin_amdgcn_global_load_lds(
            (const __attribute__((address_space(1))) unsigned int*)gp,
            (__attribute__((address_space(3))) unsigned int*)(fbuf + f),
            4, 0, 0);
    }
}

// fbuf (f32) -> f16 tile with exact R0 semantics: RNE (_Float16) cast and
// zero for out-of-image taps. ds_read_b64 stride-8B (2-way, free) + b32 write.
__device__ __forceinline__ void convert_tile(const float* fbuf, h2_t* tdst,
                                             int tid, int tiley, int tilex) {
    #pragma unroll
    for (int i = 0; i < 6; ++i) {
        const int t = tid + i * NT;
        if (t < TILEW) {
            const int r = t / TWORDS;
            const int w = t - r * TWORDS;    // h2 word -> float cols 2w, 2w+1
            const int gy = tiley - 15 + r;
            const int gx = tilex - 15 + 2 * w;
            const bool rowok = (unsigned)gy < (unsigned)HH;
            f2_t v = *(const f2_t*)(fbuf + r * FSTR + 2 * w);
            float v0 = (rowok && (unsigned)gx       < (unsigned)WW) ? v[0] : 0.f;
            float v1 = (rowok && (unsigned)(gx + 1) < (unsigned)WW) ? v[1] : 0.f;
            h2_t pv; pv.x = (_Float16)v0; pv.y = (_Float16)v1;
            tdst[t] = pv;
        }
    }
}

__launch_bounds__(512, 2)
__global__ void defocus_kernel(const float* __restrict__ img,
                               const float* __restrict__ coc,
                               float* __restrict__ out) {
    const int tx = threadIdx.x;            // 0..15
    const int ty = threadIdx.y;            // 0..31
    const int tid = ty * 16 + tx;
    const int tilex = blockIdx.x * TXO;
    const int tiley = blockIdx.y * TYO;
    const int b = blockIdx.z;

    __shared__ __align__(16) h2_t  wtab[NP * WSTR];   //  4608 B
    __shared__ __align__(16) h2_t  tile[3 * TILEW];   // 35712 B
    __shared__ __align__(16) float fbuf[FBUFW];       // 24576 B   (total 64896)

    const int yo = tiley + ty;
    const int xo = tilex + tx * 4;

    // ---- (1) coc load FIRST (oldest vmcnt entry: bin search waits only on it)
    const float4 cv = *(const float4*)&coc[((size_t)b * HH + yo) * WW + xo];

    // ---- (2) fire channel 0's staging into fbuf (no registers held)
    issue_stage(img + (size_t)(b * CC) * HH * WW, fbuf, tid, tiley, tilex);

    // ---- (3) wtab build (VALU/f64 + shfl only; overlaps outstanding loads)
    {
        const int t = tid & 31;               // padded tap position 0..31
        #pragma unroll
        for (int pass = 0; pass < 2; ++pass) {
            const int p = (tid >> 5) + 16 * pass;   // plane 0..31
            const double stepd = 50.0 / 31.0;
            double cocp = (p < 31) ? (double)p * stepd : 50.0;  // numpy linspace
            float gt;
            if (cocp < 0.5) {
                gt = (t == 15) ? 1.f : 0.f;   // identity plane (plane 0 only)
            } else {
                double sigma = cocp / 2.355;
                int k = (int)(2.0 * cocp + 1.0);   // trunc, matches python int()
                if ((k & 1) == 0) k += 1;
                if (k > KC) k = KC;
                int h = k / 2;
                int d = t - 15;
                float denom = (float)(2.0 * sigma * sigma);
                float v = (d >= -h && d <= h && t < KC) ? expf(-(float)(d * d) / denom) : 0.f;
                float s = v;
                #pragma unroll
                for (int off = 1; off < 32; off <<= 1) s += __shfl_xor(s, off, 32);
                gt = v / s;
            }
            const int m = t & 15;
            const int s0 = (t < 16) ? (2 * m) : ((2 * m - 1 < 0) ? 0 : 2 * m - 1);
            const int s1 = (t < 16) ? (2 * m + 1) : (2 * m);
            float w0 = __shfl(gt, s0, 32);
            float w1 = __shfl(gt, s1, 32);
            if (t >= 16 && (2 * m - 1) < 0) w0 = 0.f;   // g[-1] = 0
            h2_t w; w.x = (_Float16)w0; w.y = (_Float16)w1;
            wtab[p * WSTR + t] = w;
            if (t < WSTR - 32) {
                h2_t z; z.x = (_Float16)0.f; z.y = (_Float16)0.f;
                wtab[p * WSTR + 32 + t] = z;
            }
        }
    }

    // ---- (4) per-pixel bin index (waits only cv: it is the oldest vmem op)
    const float cocf[4] = {cv.x, cv.y, cv.z, cv.w};
    int idx[4];
    #pragma unroll
    for (int j = 0; j < 4; ++j) {
        const double stepd = 50.0 / 31.0;
        double cd = (double)cocf[j];
        int i0 = (int)floor(cd / stepd + 0.5);
        i0 = min(max(i0, 0), 31);
        if (i0 > 0 && cd <= 0.5 * (plane_of(i0 - 1) + plane_of(i0))) {
            i0 -= 1;
        } else if (i0 < 31 && cd > 0.5 * (plane_of(i0) + plane_of(i0 + 1))) {
            i0 += 1;
        }
        idx[j] = i0;
    }

    __syncthreads();   // drains vmcnt: fbuf(ch0) + wtab ready

    // ---- (5) convert ch0 into tile 0
    convert_tile(fbuf, tile, tid, tiley, tilex);

    __syncthreads();   // tile0 ready, fbuf free for ch1

    // ---- (6) gather this thread's 4 weight rows into registers
    // even local col (j=0,2): phase A; odd (j=1,3): phase B (pre-shifted one tap)
    h2_t wj[4][16];
    #pragma unroll
    for (int j = 0; j < 4; ++j) {
        const h2_t* wp = &wtab[idx[j] * WSTR + (j & 1) * 16];
        #pragma unroll
        for (int m = 0; m < 4; ++m) {
            h8_t v = *(const h8_t*)(wp + 4 * m);   // 16B aligned: WSTR%4==0
            #pragma unroll
            for (int q = 0; q < 4; ++q) {
                h2_t t2; t2.x = v[2 * q]; t2.y = v[2 * q + 1];
                wj[j][4 * m + q] = t2;
            }
        }
    }

    // ---- (7) pipelined channels: fire gll c+1, compute c, convert c+1
    #pragma unroll 1
    for (int c = 0; c < CC; ++c) {
        if (c + 1 < CC)   // zero-register prefetch of next channel into fbuf
            issue_stage(img + (size_t)(b * CC + c + 1) * HH * WW, fbuf,
                        tid, tiley, tilex);

        float acc0 = 0.f, acc1 = 0.f, acc2 = 0.f, acc3 = 0.f;
        const h2_t* rowbase = &tile[c * TILEW + ty * TWORDS + 2 * tx];
        #pragma unroll
        for (int dy = 0; dy < KC; ++dy) {
            const h2_t* rp = rowbase + dy * TWORDS;
            h2_t rw[18];
            #pragma unroll
            for (int m = 0; m < 9; ++m) {
                h4_t q = *(const h4_t*)(rp + 2 * m);   // ds_read_b64, conflict-free
                h2_t lo; lo.x = q[0]; lo.y = q[1];
                h2_t hi; hi.x = q[2]; hi.y = q[3];
                rw[2 * m]     = lo;
                rw[2 * m + 1] = hi;
            }
            float rs0 = 0.f, rs1 = 0.f, rs2 = 0.f, rs3 = 0.f;
            #pragma unroll
            for (int m = 0; m < 16; ++m) {
                rs0 = __builtin_amdgcn_fdot2(wj[0][m], rw[m],     rs0, false);
                rs1 = __builtin_amdgcn_fdot2(wj[1][m], rw[m],     rs1, false);
                rs2 = __builtin_amdgcn_fdot2(wj[2][m], rw[m + 1], rs2, false);
                rs3 = __builtin_amdgcn_fdot2(wj[3][m], rw[m + 1], rs3, false);
            }
            // column taps g[dy] from the same registers (dy unrolled -> static)
            float cw0, cw1, cw2, cw3;
            if ((dy & 1) == 0) {
                cw0 = (float)wj[0][dy >> 1].x;           // A: lo = g[dy]
                cw2 = (float)wj[2][dy >> 1].x;
                cw1 = (float)wj[1][dy >> 1].y;           // B: hi = g[dy]
                cw3 = (float)wj[3][dy >> 1].y;
            } else {
                cw0 = (float)wj[0][dy >> 1].y;           // A: hi = g[dy]
                cw2 = (float)wj[2][dy >> 1].y;
                cw1 = (float)wj[1][(dy + 1) >> 1].x;     // B: lo of next = g[dy]
                cw3 = (float)wj[3][(dy + 1) >> 1].x;
            }
            acc0 += cw0 * rs0;
            acc1 += cw1 * rs1;
            acc2 += cw2 * rs2;
            acc3 += cw3 * rs3;
        }

        *(float4*)&out[((size_t)(b * CC + c) * HH + yo) * WW + xo] =
            make_float4(acc0, acc1, acc2, acc3);

        if (c + 1 < CC) {
            __syncthreads();   // drains vmcnt: fbuf(c+1) landed long ago
            convert_tile(fbuf, tile + (c + 1) * TILEW, tid, tiley, tilex);
            __syncthreads();   // tile c+1 ready, fbuf free for c+2
        }
    }
}

extern "C" void kernel_launch(void* const* d_in, const int* in_sizes, int n_in,
                              void* d_out, int out_size, void* d_ws, size_t ws_size,
                              hipStream_t stream) {
    const float* sharp = (const float*)d_in[0];
    const float* cocm  = (const float*)d_in[1];
    float* out = (float*)d_out;

    dim3 grid(WW / TXO, HH / TYO, BB);
    dim3 block(16, 32, 1);
    defocus_kernel<<<grid, block, 0, stream>>>(sharp, cocm, out);
}

// Round 4
// 135.111 us; speedup vs baseline: 1.2561x; 1.2561x over previous
//
#include <hip/hip_runtime.h>
#include <math.h>

typedef _Float16 h2_t __attribute__((ext_vector_type(2)));
typedef _Float16 h4_t __attribute__((ext_vector_type(4)));
typedef _Float16 h8_t __attribute__((ext_vector_type(8)));

#define NP 32
#define KC 31
#define HH 512
#define WW 512
#define BB 4
#define CC 3

#define TXO 64        // 64-wide tile, 512-thread block
#define TYO 32
#define NT 512        // threads per block
#define TROWS 62      // 32 outputs + 15 + 15 halo
#define TWORDS 48     // row stride in h2 words
#define WSTR 36       // weight table plane stride in h2 words

// HARD CONSTRAINTS (measured R0-R3):
//  - grid z = BB (channel-split -> GB-scale scratch traffic)
//  - >128 VGPRs unobtainable -> 4 outputs/thread; wj[64] dominates the budget
//  - insert-style unpack (shuffles -20%); fdot2 == pk_fma rate -> dy-loop FINAL
//  - NO staging may coexist with the wj-resident compute loop. Proven 3x:
//    R1 (36 regs held) WRITE 12->15MB spill; R2 (12 regs across dy-loop)
//    WRITE->52MB; R3 (global_load_lds, "zero-reg") WRITE->92MB + FETCH loses
//    all L2 halo reuse (37MB). Stage-then-compute with barriers is the floor.
// THIS ROUND: R0's exact structure (fastest measured kernel: 84us, VALU 60%,
// WRITE 12.3MB) made single-dispatch (in-block wtab build, verified
// bit-identical for 3 rounds) to keep R1's measured ~26us bench-overhead win.

__device__ __forceinline__ double plane_of(int i) {
    const double stepd = 50.0 / 31.0;
    return (i < 31) ? (double)i * stepd : 50.0;
}

__launch_bounds__(512, 2)
__global__ void defocus_kernel(const float* __restrict__ img,
                               const float* __restrict__ coc,
                               float* __restrict__ out) {
    const int tx = threadIdx.x;            // 0..15
    const int ty = threadIdx.y;            // 0..31
    const int tid = ty * 16 + tx;
    const int tilex = blockIdx.x * TXO;
    const int tiley = blockIdx.y * TYO;
    const int b = blockIdx.z;

    __shared__ __align__(16) h2_t wtab[NP * WSTR];
    __shared__ __align__(16) h2_t tile[TROWS * TWORDS];

    const int yo = tiley + ty;
    const int xo = tilex + tx * 4;

    // ---- (1) coc load first; its latency hides under the wtab build
    const float4 cv = *(const float4*)&coc[((size_t)b * HH + yo) * WW + xo];

    // ---- (2) in-block wtab build (replaces the init dispatch; bit-identical:
    //          verified absmax-stable across R1/R2/R3). Pure VALU/f64 + shfl.
    {
        const int t = tid & 31;               // padded tap position 0..31
        #pragma unroll
        for (int pass = 0; pass < 2; ++pass) {
            const int p = (tid >> 5) + 16 * pass;   // plane 0..31
            const double stepd = 50.0 / 31.0;
            double cocp = (p < 31) ? (double)p * stepd : 50.0;  // numpy linspace
            float gt;
            if (cocp < 0.5) {
                gt = (t == 15) ? 1.f : 0.f;   // identity plane (plane 0 only)
            } else {
                double sigma = cocp / 2.355;
                int k = (int)(2.0 * cocp + 1.0);   // trunc, matches python int()
                if ((k & 1) == 0) k += 1;
                if (k > KC) k = KC;
                int h = k / 2;
                int d = t - 15;
                float denom = (float)(2.0 * sigma * sigma);
                float v = (d >= -h && d <= h && t < KC) ? expf(-(float)(d * d) / denom) : 0.f;
                float s = v;
                #pragma unroll
                for (int off = 1; off < 32; off <<= 1) s += __shfl_xor(s, off, 32);
                gt = v / s;
            }
            const int m = t & 15;
            const int s0 = (t < 16) ? (2 * m) : ((2 * m - 1 < 0) ? 0 : 2 * m - 1);
            const int s1 = (t < 16) ? (2 * m + 1) : (2 * m);
            float w0 = __shfl(gt, s0, 32);
            float w1 = __shfl(gt, s1, 32);
            if (t >= 16 && (2 * m - 1) < 0) w0 = 0.f;   // g[-1] = 0
            h2_t w; w.x = (_Float16)w0; w.y = (_Float16)w1;
            wtab[p * WSTR + t] = w;
            if (t < WSTR - 32) {
                h2_t z; z.x = (_Float16)0.f; z.y = (_Float16)0.f;
                wtab[p * WSTR + 32 + t] = z;
            }
        }
    }

    // ---- (3) per-pixel bin index, exact double-precision boundary semantics
    const float cocf[4] = {cv.x, cv.y, cv.z, cv.w};
    int idx[4];
    #pragma unroll
    for (int j = 0; j < 4; ++j) {
        const double stepd = 50.0 / 31.0;
        double cd = (double)cocf[j];
        int i0 = (int)floor(cd / stepd + 0.5);
        i0 = min(max(i0, 0), 31);
        if (i0 > 0 && cd <= 0.5 * (plane_of(i0 - 1) + plane_of(i0))) {
            i0 -= 1;
        } else if (i0 < 31 && cd > 0.5 * (plane_of(i0) + plane_of(i0 + 1))) {
            i0 += 1;
        }
        idx[j] = i0;
    }

    __syncthreads();  // wtab staged

    // ---- (4) gather this thread's 4 weight rows into registers
    // even local col (j=0,2): phase A; odd (j=1,3): phase B (pre-shifted one tap)
    h2_t wj[4][16];
    #pragma unroll
    for (int j = 0; j < 4; ++j) {
        const h2_t* wp = &wtab[idx[j] * WSTR + (j & 1) * 16];
        #pragma unroll
        for (int m = 0; m < 4; ++m) {
            h8_t v = *(const h8_t*)(wp + 4 * m);   // 16B aligned: WSTR%4==0
            #pragma unroll
            for (int q = 0; q < 4; ++q) {
                h2_t t2; t2.x = v[2 * q]; t2.y = v[2 * q + 1];
                wj[j][4 * m + q] = t2;
            }
        }
    }

    // ---- (5) per-channel: stage -> sync -> compute (R0-verbatim, the fastest
    //          measured structure; nothing register-live across phases)
    for (int c = 0; c < CC; ++c) {
        __syncthreads();  // previous channel's readers done
        const float* src = img + (size_t)(b * CC + c) * HH * WW;
        for (int f = tid; f < TROWS * TWORDS; f += NT) {
            int r = f / TWORDS;
            int w = f - r * TWORDS;
            int gy = tiley - 15 + r;
            int gx = tilex - 15 + 2 * w;
            float v0 = 0.f, v1 = 0.f;
            if ((unsigned)gy < (unsigned)HH) {
                if ((unsigned)gx < (unsigned)WW) v0 = src[gy * WW + gx];
                if ((unsigned)(gx + 1) < (unsigned)WW) v1 = src[gy * WW + gx + 1];
            }
            h2_t pv; pv.x = (_Float16)v0; pv.y = (_Float16)v1;
            tile[f] = pv;
        }
        __syncthreads();

        float acc0 = 0.f, acc1 = 0.f, acc2 = 0.f, acc3 = 0.f;
        const h2_t* rowbase = &tile[ty * TWORDS + 2 * tx];
        #pragma unroll
        for (int dy = 0; dy < KC; ++dy) {
            const h2_t* rp = rowbase + dy * TWORDS;
            h2_t rw[18];
            #pragma unroll
            for (int m = 0; m < 9; ++m) {
                h4_t q = *(const h4_t*)(rp + 2 * m);   // ds_read_b64, conflict-free
                h2_t lo; lo.x = q[0]; lo.y = q[1];
                h2_t hi; hi.x = q[2]; hi.y = q[3];
                rw[2 * m]     = lo;
                rw[2 * m + 1] = hi;
            }
            float rs0 = 0.f, rs1 = 0.f, rs2 = 0.f, rs3 = 0.f;
            #pragma unroll
            for (int m = 0; m < 16; ++m) {
                rs0 = __builtin_amdgcn_fdot2(wj[0][m], rw[m],     rs0, false);
                rs1 = __builtin_amdgcn_fdot2(wj[1][m], rw[m],     rs1, false);
                rs2 = __builtin_amdgcn_fdot2(wj[2][m], rw[m + 1], rs2, false);
                rs3 = __builtin_amdgcn_fdot2(wj[3][m], rw[m + 1], rs3, false);
            }
            // column taps g[dy] from the same registers (dy unrolled -> static)
            float cw0, cw1, cw2, cw3;
            if ((dy & 1) == 0) {
                cw0 = (float)wj[0][dy >> 1].x;           // A: lo = g[dy]
                cw2 = (float)wj[2][dy >> 1].x;
                cw1 = (float)wj[1][dy >> 1].y;           // B: hi = g[dy]
                cw3 = (float)wj[3][dy >> 1].y;
            } else {
                cw0 = (float)wj[0][dy >> 1].y;           // A: hi = g[dy]
                cw2 = (float)wj[2][dy >> 1].y;
                cw1 = (float)wj[1][(dy + 1) >> 1].x;     // B: lo of next = g[dy]
                cw3 = (float)wj[3][(dy + 1) >> 1].x;
            }
            acc0 += cw0 * rs0;
            acc1 += cw1 * rs1;
            acc2 += cw2 * rs2;
            acc3 += cw3 * rs3;
        }

        *(float4*)&out[((size_t)(b * CC + c) * HH + yo) * WW + xo] =
            make_float4(acc0, acc1, acc2, acc3);
    }
}

extern "C" void kernel_launch(void* const* d_in, const int* in_sizes, int n_in,
                              void* d_out, int out_size, void* d_ws, size_t ws_size,
                              hipStream_t stream) {
    const float* sharp = (const float*)d_in[0];
    const float* cocm  = (const float*)d_in[1];
    float* out = (float*)d_out;

    dim3 grid(WW / TXO, HH / TYO, BB);
    dim3 block(16, 32, 1);
    defocus_kernel<<<grid, block, 0, stream>>>(sharp, cocm, out);
}